// Round 1
// baseline (245.592 us; speedup 1.0000x reference)
//
#include <hip/hip_runtime.h>
#include <hip/hip_bf16.h>
#include <stdint.h>

#define BQ   8
#define SEQ  2048
#define EMB  512

typedef __attribute__((ext_vector_type(8))) short short8;
typedef __attribute__((ext_vector_type(4))) float floatx4;
typedef __attribute__((ext_vector_type(4))) unsigned short ushort4_t;
typedef __hip_bfloat16 bf16;

__device__ __forceinline__ unsigned short f2bf(float f) {
    union { bf16 h; unsigned short u; } c;
    c.h = __float2bfloat16(f);
    return c.u;
}
__device__ __forceinline__ float bf2f(unsigned short u) {
    union { unsigned int i; float f; } c;
    c.i = ((unsigned int)u) << 16;
    return c.f;
}

// ---------------- fp32 -> bf16 convert (optionally scaled) ----------------
__global__ __launch_bounds__(256) void cvt_f32_to_bf16(
    const float* __restrict__ in, bf16* __restrict__ out, long n4, float scale)
{
    long i = (long)blockIdx.x * 256 + threadIdx.x;
    if (i >= n4) return;
    floatx4 v = *(const floatx4*)(in + i * 4);
    ushort4_t o;
    o.x = f2bf(v.x * scale);
    o.y = f2bf(v.y * scale);
    o.z = f2bf(v.z * scale);
    o.w = f2bf(v.w * scale);
    *(ushort4_t*)((unsigned short*)out + i * 4) = o;
}

// ---------------- mask(bool, stored as int32 OR uint8) -> f32 bias --------
__global__ __launch_bounds__(256) void mask_to_bias(
    const void* __restrict__ mraw, float* __restrict__ bias)
{
    __shared__ int bad;
    int tid = threadIdx.x;
    if (tid == 0) bad = 0;
    __syncthreads();
    const int* mi = (const int*)mraw;
    int local = 0;
    for (int i = tid; i < 4096; i += 256) {          // first 16KB, safe in both layouts
        unsigned v = (unsigned)mi[i];
        if (v > 1u) local = 1;
    }
    if (local) atomicOr(&bad, 1);
    __syncthreads();
    bool as_int = (bad == 0);
    const unsigned char* mb = (const unsigned char*)mraw;
    for (int i = tid; i < BQ * SEQ; i += 256) {
        int mv = as_int ? mi[i] : (int)mb[i];
        bias[i] = mv ? -1e9f : 0.0f;
    }
}

// ---------------- B^T GEMM: C[m][n] = sum_k A[m][k]*Bt[n][k] --------------
// 128x128 tile, 4 waves (2x2 of 64x64), 16x16x32 bf16 MFMA, BK=32,
// global_load_lds width-16 staging (m97 structure).
enum { EPI_BF16 = 0, EPI_TRANS = 1, EPI_S = 2, EPI_F32 = 3 };

template <int EPI>
__global__ __launch_bounds__(256) void gemm_bt(
    const bf16* __restrict__ A, const bf16* __restrict__ Bt,
    void* __restrict__ C, const float* __restrict__ bias,
    int Ncols, int K, long strideA, long strideB)
{
    __shared__ __attribute__((aligned(16))) bf16 lA[128 * 32];
    __shared__ __attribute__((aligned(16))) bf16 lB[128 * 32];

    const int tid  = threadIdx.x;
    const int lane = tid & 63;
    const int wv   = tid >> 6;
    const int wr   = wv >> 1, wc = wv & 1;
    const int z    = blockIdx.z;
    const long brow = (long)blockIdx.y * 128;
    const long bcol = (long)blockIdx.x * 128;
    const bf16* Ab = A + (long)z * strideA;
    const bf16* Bb = Bt + (long)z * strideB;

    floatx4 acc[4][4];
#pragma unroll
    for (int m = 0; m < 4; m++)
#pragma unroll
        for (int n = 0; n < 4; n++) acc[m][n] = (floatx4)0.0f;

    const int hi  = lane >> 4;   // 0..3
    const int r16 = lane & 15;

    for (int kt = 0; kt < K; kt += 32) {
        // stage A tile [128][32] (8KB = 512 x 16B chunks) and B tile
#pragma unroll
        for (int it = 0; it < 2; ++it) {
            int c = it * 256 + tid;
            const bf16* src = Ab + (brow + (c >> 2)) * (long)K + kt + (c & 3) * 8;
            __builtin_amdgcn_global_load_lds(
                (const __attribute__((address_space(1))) void*)src,
                (__attribute__((address_space(3))) void*)(&lA[(it * 256 + wv * 64) * 8]),
                16, 0, 0);
        }
#pragma unroll
        for (int it = 0; it < 2; ++it) {
            int c = it * 256 + tid;
            const bf16* src = Bb + (bcol + (c >> 2)) * (long)K + kt + (c & 3) * 8;
            __builtin_amdgcn_global_load_lds(
                (const __attribute__((address_space(1))) void*)src,
                (__attribute__((address_space(3))) void*)(&lB[(it * 256 + wv * 64) * 8]),
                16, 0, 0);
        }
        __syncthreads();

        short8 af[4], bfr[4];
#pragma unroll
        for (int m = 0; m < 4; m++)
            af[m] = *(const short8*)&lA[(wr * 64 + m * 16 + r16) * 32 + hi * 8];
#pragma unroll
        for (int n = 0; n < 4; n++)
            bfr[n] = *(const short8*)&lB[(wc * 64 + n * 16 + r16) * 32 + hi * 8];
#pragma unroll
        for (int m = 0; m < 4; m++)
#pragma unroll
            for (int n = 0; n < 4; n++)
                acc[m][n] = __builtin_amdgcn_mfma_f32_16x16x32_bf16(
                    af[m], bfr[n], acc[m][n], 0, 0, 0);
        __syncthreads();
    }

    // epilogue: C/D layout col=lane&15, row=(lane>>4)*4+j  (m89-verified)
#pragma unroll
    for (int m = 0; m < 4; m++) {
#pragma unroll
        for (int n = 0; n < 4; n++) {
#pragma unroll
            for (int j = 0; j < 4; j++) {
                long row = brow + wr * 64 + m * 16 + hi * 4 + j;
                long col = bcol + wc * 64 + n * 16 + r16;
                float v = acc[m][n][j];
                if constexpr (EPI == EPI_BF16) {
                    ((bf16*)C)[row * (long)Ncols + col] = __float2bfloat16(v);
                } else if constexpr (EPI == EPI_TRANS) {
                    long bb = row >> 11, t = row & 2047;   // Vt[b][e][n]
                    ((bf16*)C)[(bb * EMB + col) * SEQ + t] = __float2bfloat16(v);
                } else if constexpr (EPI == EPI_S) {
                    v += bias[(long)z * SEQ + col];
                    ((bf16*)C)[((long)z * SEQ + row) * SEQ + col] = __float2bfloat16(v);
                } else { // EPI_F32
                    ((float*)C)[((long)z * SEQ + row) * EMB + col] = v;
                }
            }
        }
    }
}

// ---------------- in-place row softmax over 2048 bf16 scores --------------
__global__ __launch_bounds__(256) void softmax_inplace(bf16* __restrict__ S)
{
    __shared__ float red[8];
    long rowBase = (long)blockIdx.x * SEQ;
    int tid = threadIdx.x;
    int lane = tid & 63, wv = tid >> 6;
    unsigned short* Sp = (unsigned short*)S;

    short8 raw = *(const short8*)(Sp + rowBase + tid * 8);
    float f[8];
#pragma unroll
    for (int j = 0; j < 8; j++) f[j] = bf2f((unsigned short)raw[j]);

    float mx = f[0];
#pragma unroll
    for (int j = 1; j < 8; j++) mx = fmaxf(mx, f[j]);
    for (int o = 32; o; o >>= 1) mx = fmaxf(mx, __shfl_xor(mx, o));
    if (lane == 0) red[wv] = mx;
    __syncthreads();
    mx = fmaxf(fmaxf(red[0], red[1]), fmaxf(red[2], red[3]));

    float e[8], s = 0.f;
#pragma unroll
    for (int j = 0; j < 8; j++) { e[j] = __expf(f[j] - mx); s += e[j]; }
    for (int o = 32; o; o >>= 1) s += __shfl_xor(s, o);
    if (lane == 0) red[4 + wv] = s;
    __syncthreads();
    float inv = 1.0f / (red[4] + red[5] + red[6] + red[7]);

    short8 outv;
#pragma unroll
    for (int j = 0; j < 8; j++) outv[j] = (short)f2bf(e[j] * inv);
    *(short8*)(Sp + rowBase + tid * 8) = outv;
}

// --------------------------------------------------------------------------
extern "C" void kernel_launch(void* const* d_in, const int* in_sizes, int n_in,
                              void* d_out, int out_size, void* d_ws, size_t ws_size,
                              hipStream_t stream)
{
    const float* feat = (const float*)d_in[0];
    const void*  mask = d_in[1];
    const float* Wq   = (const float*)d_in[2];
    const float* Wk   = (const float*)d_in[3];
    const float* Wv   = (const float*)d_in[4];
    float* out = (float*)d_out;

    const long M   = (long)BQ * SEQ;       // 16384
    const long NE  = M * EMB;              // 8.39M elems
    const long NW  = (long)EMB * EMB;      // 262144 elems

    char* ws = (char*)d_ws;
    size_t off = 0;
    auto carve = [&](size_t bytes) -> void* {
        void* p = ws + off;
        off = (off + bytes + 4095) & ~(size_t)4095;
        return p;
    };
    bf16*  Xb   = (bf16*)carve(NE * 2);
    bf16*  Wqb  = (bf16*)carve(NW * 2);
    bf16*  Wkb  = (bf16*)carve(NW * 2);
    bf16*  Wvb  = (bf16*)carve(NW * 2);
    bf16*  Qb   = (bf16*)carve(NE * 2);
    bf16*  Kb   = (bf16*)carve(NE * 2);
    bf16*  Vt   = (bf16*)carve(NE * 2);
    float* bias = (float*)carve(M * 4);
    bf16*  S    = (bf16*)carve((long)BQ * SEQ * SEQ * 2);
    (void)ws_size; (void)in_sizes; (void)n_in; (void)out_size;

    const float qscale = 0.04419417382415922f;  // 512^-0.5 folded into Wq

    cvt_f32_to_bf16<<<dim3((NE / 4 + 255) / 256), dim3(256), 0, stream>>>(feat, Xb, NE / 4, 1.0f);
    cvt_f32_to_bf16<<<dim3((NW / 4 + 255) / 256), dim3(256), 0, stream>>>(Wq, Wqb, NW / 4, qscale);
    cvt_f32_to_bf16<<<dim3((NW / 4 + 255) / 256), dim3(256), 0, stream>>>(Wk, Wkb, NW / 4, 1.0f);
    cvt_f32_to_bf16<<<dim3((NW / 4 + 255) / 256), dim3(256), 0, stream>>>(Wv, Wvb, NW / 4, 1.0f);
    mask_to_bias<<<dim3(1), dim3(256), 0, stream>>>(mask, bias);

    // Q = X @ (Wq*scale)^T ; K = X @ Wk^T ; V^T via transposed write
    gemm_bt<EPI_BF16><<<dim3(4, 128, 1), dim3(256), 0, stream>>>(Xb, Wqb, Qb, nullptr, EMB, EMB, 0, 0);
    gemm_bt<EPI_BF16><<<dim3(4, 128, 1), dim3(256), 0, stream>>>(Xb, Wkb, Kb, nullptr, EMB, EMB, 0, 0);
    gemm_bt<EPI_TRANS><<<dim3(4, 128, 1), dim3(256), 0, stream>>>(Xb, Wvb, Vt, nullptr, EMB, EMB, 0, 0);

    // S[b] = (Q*scale)[b] @ K[b]^T + mask bias   (bf16, 64MB)
    gemm_bt<EPI_S><<<dim3(16, 16, BQ), dim3(256), 0, stream>>>(
        Qb, Kb, S, bias, SEQ, EMB, (long)SEQ * EMB, (long)SEQ * EMB);

    // row softmax in place
    softmax_inplace<<<dim3(BQ * SEQ), dim3(256), 0, stream>>>(S);

    // out[b] = P[b] @ V[b]  ==  P[b] @ Vt[b]^T   (f32 out)
    gemm_bt<EPI_F32><<<dim3(4, 16, BQ), dim3(256), 0, stream>>>(
        S, Vt, out, nullptr, EMB, SEQ, (long)SEQ * SEQ, (long)EMB * SEQ);
}